// Round 6
// baseline (467.304 us; speedup 1.0000x reference)
//
#include <hip/hip_runtime.h>
#include <hip/hip_bf16.h>

typedef unsigned short ushort_t;
typedef __attribute__((ext_vector_type(8))) short short8;
typedef __attribute__((ext_vector_type(4))) float f32x4;

#define HIDDEN 256
#define N_NODES 50000
#define BM 64
#define LDSROW 512   // fused-fallback LDS row stride (swizzled slots)

__device__ __forceinline__ unsigned int f2bf(float f) {
    union { float f; unsigned int i; } v; v.f = f;
    return (v.i + 0x7fffu + ((v.i >> 16) & 1u)) >> 16;
}
__device__ __forceinline__ float bf2f(unsigned int u) {
    union { unsigned int i; float f; } v; v.i = u << 16; return v.f;
}

// ws layout (bytes)
#define OFF_MVB    0u                         // 50000*256 bf16 = 25,600,000
#define OFF_WB     25600000u                  // 65536 bf16
#define OFF_CNT    25731072u                  // int[50000]
#define OFF_OFFS   25931072u                  // int[50001]
#define OFF_CUR    26131076u                  // int[50000]
#define OFF_ELIST  26331076u                  // int[300000]
#define OFF_BSUM   27531076u                  // int[256]
#define OFF_AB     27800000u                  // 300000*256 bf16 = 153,600,000
#define WS_NEED_SPLIT (OFF_AB + 153600000u)

#define SCAN_NBLK ((N_NODES + 255) / 256)     // 196

// Kernel 0: W fp32 -> bf16
__global__ void convert_w(const float* __restrict__ W, ushort_t* __restrict__ Wb, int n) {
    int i = blockIdx.x * blockDim.x + threadIdx.x;
    if (i < n) Wb[i] = (ushort_t)f2bf(W[i]);
}

// Kernel 1: histogram of dst
__global__ void count_dst(const int* __restrict__ dst, int* __restrict__ cnt, int n) {
    int i = blockIdx.x * blockDim.x + threadIdx.x;
    if (i < n) atomicAdd(&cnt[dst[i]], 1);
}

// Kernel 2a: per-256-block exclusive scan, block sums out
__global__ __launch_bounds__(256)
void block_scan(const int* __restrict__ cnt, int* __restrict__ offs,
                int* __restrict__ bsum) {
    __shared__ int sh[256];
    const int t = threadIdx.x;
    const int idx = blockIdx.x * 256 + t;
    int v = (idx < N_NODES) ? cnt[idx] : 0;
    sh[t] = v;
    __syncthreads();
    for (int off = 1; off < 256; off <<= 1) {
        int x = (t >= off) ? sh[t - off] : 0;
        __syncthreads();
        sh[t] += x;
        __syncthreads();
    }
    if (idx < N_NODES) offs[idx] = sh[t] - v;
    if (t == 255) bsum[blockIdx.x] = sh[255];
}

// Kernel 2b: exclusive scan of block sums (single block)
__global__ __launch_bounds__(256)
void scan_bsum(int* __restrict__ bsum, int nb) {
    __shared__ int sh[256];
    const int t = threadIdx.x;
    int v = (t < nb) ? bsum[t] : 0;
    sh[t] = v;
    __syncthreads();
    for (int off = 1; off < 256; off <<= 1) {
        int x = (t >= off) ? sh[t - off] : 0;
        __syncthreads();
        sh[t] += x;
        __syncthreads();
    }
    if (t < nb) bsum[t] = sh[t] - v;
}

// Kernel 2c: offs += base; cur = offs; offs[N] = n_edges
__global__ __launch_bounds__(256)
void add_base(int* __restrict__ offs, const int* __restrict__ bsum,
              int* __restrict__ cur, int n_edges) {
    const int idx = blockIdx.x * 256 + threadIdx.x;
    if (idx < N_NODES) {
        int o = offs[idx] + bsum[idx >> 8];
        offs[idx] = o;
        cur[idx] = o;
    }
    if (idx == 0) offs[N_NODES] = n_edges;
}

// Kernel 3: bucket edge ids by destination
__global__ void fill_elist(const int* __restrict__ dst, int* __restrict__ cur,
                           int* __restrict__ elist, int n) {
    int i = blockIdx.x * blockDim.x + threadIdx.x;
    if (i < n) {
        int d = dst[i];
        int pos = atomicAdd(&cur[d], 1);
        elist[pos] = i;
    }
}

// Kernel 4: per-node register-accumulated relu-sum -> Mv (bf16)
__global__ __launch_bounds__(256)
void node_gather_sum(const float* __restrict__ E,
                     const int* __restrict__ offs,
                     const int* __restrict__ elist,
                     unsigned int* __restrict__ Mvb) {
    const int node = blockIdx.x * 4 + (threadIdx.x >> 6);
    const int lane = threadIdx.x & 63;
    if (node >= N_NODES) return;
    const int s0 = offs[node];
    const int s1 = offs[node + 1];
    float4 acc = {0.f, 0.f, 0.f, 0.f};
    int j = s0;
    for (; j + 4 <= s1; j += 4) {
        const int e0 = elist[j], e1 = elist[j + 1], e2 = elist[j + 2], e3 = elist[j + 3];
        float4 v0 = *(const float4*)(E + (size_t)e0 * HIDDEN + lane * 4);
        float4 v1 = *(const float4*)(E + (size_t)e1 * HIDDEN + lane * 4);
        float4 v2 = *(const float4*)(E + (size_t)e2 * HIDDEN + lane * 4);
        float4 v3 = *(const float4*)(E + (size_t)e3 * HIDDEN + lane * 4);
        acc.x += fmaxf(v0.x, 0.f) + fmaxf(v1.x, 0.f) + fmaxf(v2.x, 0.f) + fmaxf(v3.x, 0.f);
        acc.y += fmaxf(v0.y, 0.f) + fmaxf(v1.y, 0.f) + fmaxf(v2.y, 0.f) + fmaxf(v3.y, 0.f);
        acc.z += fmaxf(v0.z, 0.f) + fmaxf(v1.z, 0.f) + fmaxf(v2.z, 0.f) + fmaxf(v3.z, 0.f);
        acc.w += fmaxf(v0.w, 0.f) + fmaxf(v1.w, 0.f) + fmaxf(v2.w, 0.f) + fmaxf(v3.w, 0.f);
    }
    for (; j < s1; ++j) {
        const int e = elist[j];
        float4 v = *(const float4*)(E + (size_t)e * HIDDEN + lane * 4);
        acc.x += fmaxf(v.x, 0.f);
        acc.y += fmaxf(v.y, 0.f);
        acc.z += fmaxf(v.z, 0.f);
        acc.w += fmaxf(v.w, 0.f);
    }
    uint2 o;
    o.x = f2bf(acc.x) | (f2bf(acc.y) << 16);
    o.y = f2bf(acc.z) | (f2bf(acc.w) << 16);
    *(uint2*)(Mvb + (size_t)node * (HIDDEN / 2) + lane * 2) = o;
}

// Kernel 5a: Ab[e] = bf16(Mv[src[e]] - relu(E[rev[e]]))
// One wave per 4 edge rows; lane-parallel over columns. All 8 row-loads
// independent and in flight; stores fully coalesced (512B/row).
__global__ __launch_bounds__(256)
void build_A(const float* __restrict__ E,
             const int* __restrict__ src,
             const int* __restrict__ rev,
             const unsigned int* __restrict__ Mvb,
             unsigned int* __restrict__ Ab, int n_edges) {
    const int wave = blockIdx.x * 4 + (threadIdx.x >> 6);
    const int lane = threadIdx.x & 63;
    const int e0 = wave * 4;
    if (e0 >= n_edges) return;
    const int nr = (n_edges - e0 < 4) ? (n_edges - e0) : 4;

    int rv[4], sv[4];
#pragma unroll
    for (int i = 0; i < 4; ++i) {
        int e = e0 + ((i < nr) ? i : 0);
        rv[i] = rev[e];
        sv[i] = src[e];
    }
    float4 ev[4];
    uint2  mv[4];
#pragma unroll
    for (int i = 0; i < 4; ++i)
        ev[i] = *(const float4*)(E + (size_t)rv[i] * HIDDEN + lane * 4);
#pragma unroll
    for (int i = 0; i < 4; ++i)
        mv[i] = *(const uint2*)(Mvb + (size_t)sv[i] * (HIDDEN / 2) + lane * 2);
#pragma unroll
    for (int i = 0; i < 4; ++i) {
        if (i < nr) {
            uint2 o;
            o.x = f2bf(bf2f(mv[i].x & 0xffffu) - fmaxf(ev[i].x, 0.f)) |
                  (f2bf(bf2f(mv[i].x >> 16)    - fmaxf(ev[i].y, 0.f)) << 16);
            o.y = f2bf(bf2f(mv[i].y & 0xffffu) - fmaxf(ev[i].z, 0.f)) |
                  (f2bf(bf2f(mv[i].y >> 16)    - fmaxf(ev[i].w, 0.f)) << 16);
            *(uint2*)(Ab + (size_t)(e0 + i) * (HIDDEN / 2) + lane * 2) = o;
        }
    }
}

// Kernel 5b: out = Ab @ W.T + b  (dense, sequential rows, no LDS)
__global__ __launch_bounds__(256)
void gemm_dense(const ushort_t* __restrict__ Ab,
                const ushort_t* __restrict__ Wb,
                const float* __restrict__ bias,
                float* __restrict__ out, int n_edges) {
    const int tid   = threadIdx.x;
    const int lane  = tid & 63;
    const int wid   = tid >> 6;
    const int l15   = lane & 15;
    const int hi16  = lane >> 4;
    const int row0  = blockIdx.x * BM;
    const int wcol0 = wid * 64;

    int rowc[4];
#pragma unroll
    for (int m = 0; m < 4; ++m) {
        int r = row0 + m * 16 + l15;
        rowc[m] = (r < n_edges) ? r : (n_edges - 1);
    }

    f32x4 acc[4][4];
#pragma unroll
    for (int m = 0; m < 4; ++m)
#pragma unroll
        for (int n = 0; n < 4; ++n)
            acc[m][n] = (f32x4){0.f, 0.f, 0.f, 0.f};

#pragma unroll 1
    for (int kk = 0; kk < 8; ++kk) {
        const int ko = kk * 32 + hi16 * 8;
        short8 a[4], bfr[4];
#pragma unroll
        for (int m = 0; m < 4; ++m)
            a[m] = *(const short8*)(Ab + (size_t)rowc[m] * HIDDEN + ko);
#pragma unroll
        for (int n = 0; n < 4; ++n) {
            const int j = wcol0 + n * 16 + l15;
            bfr[n] = *(const short8*)(Wb + (size_t)j * HIDDEN + ko);
        }
#pragma unroll
        for (int m = 0; m < 4; ++m)
#pragma unroll
            for (int n = 0; n < 4; ++n)
                acc[m][n] = __builtin_amdgcn_mfma_f32_16x16x32_bf16(a[m], bfr[n], acc[m][n], 0, 0, 0);
    }

#pragma unroll
    for (int n = 0; n < 4; ++n) {
        const int col = wcol0 + n * 16 + l15;
        const float bv = bias[col];
#pragma unroll
        for (int m = 0; m < 4; ++m) {
            const int rbase = row0 + m * 16 + hi16 * 4;
#pragma unroll
            for (int j = 0; j < 4; ++j) {
                const int row = rbase + j;
                if (row < n_edges)
                    out[(size_t)row * HIDDEN + col] = acc[m][n][j] + bv;
            }
        }
    }
}

// Fused fallback (round-5 kernel) if ws is too small for Ab.
__global__ __launch_bounds__(256, 5)
void gemm_lds(const float* __restrict__ E,
              const int* __restrict__ src,
              const int* __restrict__ rev,
              const unsigned int* __restrict__ Mvb,
              const ushort_t* __restrict__ Wb,
              const float* __restrict__ bias,
              float* __restrict__ out, int n_edges) {
    __shared__ __align__(16) unsigned char lds[BM * LDSROW];
    const int tid = threadIdx.x;
    const int row0 = blockIdx.x * BM;
    {
        const int r  = tid >> 2;
        const int q  = tid & 3;
        const int r7 = r & 7;
        const int gr = row0 + r;
        unsigned char* lrow = lds + r * LDSROW;
        if (gr < n_edges) {
            const int s  = src[gr];
            const int rv = rev[gr];
            const float4* ep = (const float4*)(E + (size_t)rv * HIDDEN + q * 64);
            const uint4* mvp = (const uint4*)(Mvb + (size_t)s * (HIDDEN / 2) + q * 32);
#pragma unroll
            for (int h = 0; h < 2; ++h) {
                float4 ev[8];
                uint4  mv[4];
#pragma unroll
                for (int i = 0; i < 8; ++i) ev[i] = ep[h * 8 + i];
#pragma unroll
                for (int i = 0; i < 4; ++i) mv[i] = mvp[h * 4 + i];
#pragma unroll
                for (int c = 0; c < 4; ++c) {
                    float4 e0 = ev[2 * c], e1 = ev[2 * c + 1];
                    uint4  m  = mv[c];
                    uint4 o;
                    o.x = f2bf(bf2f(m.x & 0xffffu) - fmaxf(e0.x, 0.f)) |
                          (f2bf(bf2f(m.x >> 16)    - fmaxf(e0.y, 0.f)) << 16);
                    o.y = f2bf(bf2f(m.y & 0xffffu) - fmaxf(e0.z, 0.f)) |
                          (f2bf(bf2f(m.y >> 16)    - fmaxf(e0.w, 0.f)) << 16);
                    o.z = f2bf(bf2f(m.z & 0xffffu) - fmaxf(e1.x, 0.f)) |
                          (f2bf(bf2f(m.z >> 16)    - fmaxf(e1.y, 0.f)) << 16);
                    o.w = f2bf(bf2f(m.w & 0xffffu) - fmaxf(e1.z, 0.f)) |
                          (f2bf(bf2f(m.w >> 16)    - fmaxf(e1.w, 0.f)) << 16);
                    const int slot = (q * 8 + h * 4 + c) ^ r7;
                    *(uint4*)(lrow + slot * 16) = o;
                }
            }
        } else {
            uint4 z = {0, 0, 0, 0};
#pragma unroll
            for (int c = 0; c < 8; ++c) *(uint4*)(lrow + ((q * 8 + c) ^ r7) * 16) = z;
        }
    }
    __syncthreads();
    const int lane  = tid & 63;
    const int wid   = tid >> 6;
    const int l15   = lane & 15;
    const int hi16  = lane >> 4;
    const int wcol0 = wid * 64;
    const int r7l   = l15 & 7;
    f32x4 acc[4][4];
#pragma unroll
    for (int m = 0; m < 4; ++m)
#pragma unroll
        for (int n = 0; n < 4; ++n)
            acc[m][n] = (f32x4){0.f, 0.f, 0.f, 0.f};
#pragma unroll 1
    for (int kk = 0; kk < 8; ++kk) {
        const int slotbyte = ((kk * 4 + hi16) ^ r7l) * 16;
        short8 a[4], bfr[4];
#pragma unroll
        for (int m = 0; m < 4; ++m)
            a[m] = *(const short8*)(lds + (m * 16 + l15) * LDSROW + slotbyte);
#pragma unroll
        for (int n = 0; n < 4; ++n)
            bfr[n] = *(const short8*)(Wb + (size_t)(wcol0 + n * 16 + l15) * HIDDEN + kk * 32 + hi16 * 8);
#pragma unroll
        for (int m = 0; m < 4; ++m)
#pragma unroll
            for (int n = 0; n < 4; ++n)
                acc[m][n] = __builtin_amdgcn_mfma_f32_16x16x32_bf16(a[m], bfr[n], acc[m][n], 0, 0, 0);
    }
#pragma unroll
    for (int n = 0; n < 4; ++n) {
        const int col = wcol0 + n * 16 + l15;
        const float bv = bias[col];
#pragma unroll
        for (int m = 0; m < 4; ++m) {
            const int rbase = row0 + m * 16 + hi16 * 4;
#pragma unroll
            for (int j = 0; j < 4; ++j) {
                const int row = rbase + j;
                if (row < n_edges)
                    out[(size_t)row * HIDDEN + col] = acc[m][n][j] + bv;
            }
        }
    }
}

extern "C" void kernel_launch(void* const* d_in, const int* in_sizes, int n_in,
                              void* d_out, int out_size, void* d_ws, size_t ws_size,
                              hipStream_t stream) {
    const float* E    = (const float*)d_in[0];
    const int*   ei   = (const int*)d_in[1];
    const int*   rev  = (const int*)d_in[2];
    const float* W    = (const float*)d_in[3];
    const float* bias = (const float*)d_in[4];
    float* out = (float*)d_out;
    const int n_edges = in_sizes[2];
    const int* srcI = ei;              // edge_index[0]
    const int* dstI = ei + n_edges;    // edge_index[1]

    char* ws = (char*)d_ws;
    unsigned int* Mvb  = (unsigned int*)(ws + OFF_MVB);
    ushort_t*     Wb   = (ushort_t*)(ws + OFF_WB);
    int*          cnt  = (int*)(ws + OFF_CNT);
    int*          offs = (int*)(ws + OFF_OFFS);
    int*          cur  = (int*)(ws + OFF_CUR);
    int*          elst = (int*)(ws + OFF_ELIST);
    int*          bsum = (int*)(ws + OFF_BSUM);
    unsigned int* Ab   = (unsigned int*)(ws + OFF_AB);

    hipMemsetAsync(cnt, 0, N_NODES * sizeof(int), stream);

    convert_w<<<(HIDDEN * HIDDEN + 255) / 256, 256, 0, stream>>>(W, Wb, HIDDEN * HIDDEN);

    count_dst<<<(n_edges + 255) / 256, 256, 0, stream>>>(dstI, cnt, n_edges);
    block_scan<<<SCAN_NBLK, 256, 0, stream>>>(cnt, offs, bsum);
    scan_bsum<<<1, 256, 0, stream>>>(bsum, SCAN_NBLK);
    add_base<<<SCAN_NBLK, 256, 0, stream>>>(offs, bsum, cur, n_edges);
    fill_elist<<<(n_edges + 255) / 256, 256, 0, stream>>>(dstI, cur, elst, n_edges);

    node_gather_sum<<<(N_NODES + 3) / 4, 256, 0, stream>>>(E, offs, elst, Mvb);

    if (ws_size >= WS_NEED_SPLIT) {
        const int nwave = (n_edges + 3) / 4;
        build_A<<<(nwave + 3) / 4, 256, 0, stream>>>(E, srcI, rev, Mvb, Ab, n_edges);
        const int nblk = (n_edges + BM - 1) / BM;
        gemm_dense<<<nblk, 256, 0, stream>>>((const ushort_t*)Ab, Wb, bias, out, n_edges);
    } else {
        const int nblk = (n_edges + BM - 1) / BM;
        gemm_lds<<<nblk, 256, 0, stream>>>(E, srcI, rev, Mvb, Wb, bias, out, n_edges);
    }
}

// Round 7
// 316.880 us; speedup vs baseline: 1.4747x; 1.4747x over previous
//
#include <hip/hip_runtime.h>
#include <hip/hip_bf16.h>

typedef unsigned short ushort_t;
typedef __attribute__((ext_vector_type(8))) short short8;
typedef __attribute__((ext_vector_type(4))) float f32x4;

#define HIDDEN 256
#define N_NODES 50000
#define BM 64
#define LDSROW 512   // bf16 row = 512B; XOR-swizzled 16B slots

__device__ __forceinline__ unsigned int f2bf(float f) {
    union { float f; unsigned int i; } v; v.f = f;
    return (v.i + 0x7fffu + ((v.i >> 16) & 1u)) >> 16;
}
__device__ __forceinline__ float bf2f(unsigned int u) {
    union { unsigned int i; float f; } v; v.i = u << 16; return v.f;
}

// ws layout (bytes)
#define OFF_MVB    0u                         // 50000*128 u32 (bf16x2) = 25,600,000
#define OFF_WF     25600000u                  // 65536 bf16 fragment-major
#define OFF_CNT    25731072u                  // int[50000]
#define OFF_OFFS   25931072u                  // int[50001]
#define OFF_CUR    26131076u                  // int[50000]
#define OFF_ELIST  26331076u                  // int[300000]
#define OFF_BSUM   27531076u                  // int[256]

#define SCAN_NBLK ((N_NODES + 255) / 256)     // 196

// Kernel 0: pack W fp32 -> bf16 fragment-major.
// Wf[(((g*8)+kk)*64 + lane)*8 + t] = W[g*16 + (lane&15)][kk*32 + (lane>>4)*8 + t]
// so gemm's fragment load is lane-contiguous 16B (1KB/instruction).
__global__ void convert_w_frag(const float* __restrict__ W, ushort_t* __restrict__ Wf, int n) {
    int i = blockIdx.x * blockDim.x + threadIdx.x;
    if (i >= n) return;
    const int t    = i & 7;
    const int lane = (i >> 3) & 63;
    const int kk   = (i >> 9) & 7;
    const int g    = i >> 12;
    const int j = g * 16 + (lane & 15);
    const int k = kk * 32 + ((lane >> 4) & 3) * 8 + t;
    Wf[i] = (ushort_t)f2bf(W[j * HIDDEN + k]);
}

// Kernel 1: histogram of dst
__global__ void count_dst(const int* __restrict__ dst, int* __restrict__ cnt, int n) {
    int i = blockIdx.x * blockDim.x + threadIdx.x;
    if (i < n) atomicAdd(&cnt[dst[i]], 1);
}

// Kernel 2a: per-256-block exclusive scan, block sums out
__global__ __launch_bounds__(256)
void block_scan(const int* __restrict__ cnt, int* __restrict__ offs,
                int* __restrict__ bsum) {
    __shared__ int sh[256];
    const int t = threadIdx.x;
    const int idx = blockIdx.x * 256 + t;
    int v = (idx < N_NODES) ? cnt[idx] : 0;
    sh[t] = v;
    __syncthreads();
    for (int off = 1; off < 256; off <<= 1) {
        int x = (t >= off) ? sh[t - off] : 0;
        __syncthreads();
        sh[t] += x;
        __syncthreads();
    }
    if (idx < N_NODES) offs[idx] = sh[t] - v;
    if (t == 255) bsum[blockIdx.x] = sh[255];
}

// Kernel 2b: exclusive scan of block sums (single block)
__global__ __launch_bounds__(256)
void scan_bsum(int* __restrict__ bsum, int nb) {
    __shared__ int sh[256];
    const int t = threadIdx.x;
    int v = (t < nb) ? bsum[t] : 0;
    sh[t] = v;
    __syncthreads();
    for (int off = 1; off < 256; off <<= 1) {
        int x = (t >= off) ? sh[t - off] : 0;
        __syncthreads();
        sh[t] += x;
        __syncthreads();
    }
    if (t < nb) bsum[t] = sh[t] - v;
}

// Kernel 2c: offs += base; cur = offs; offs[N] = n_edges
__global__ __launch_bounds__(256)
void add_base(int* __restrict__ offs, const int* __restrict__ bsum,
              int* __restrict__ cur, int n_edges) {
    const int idx = blockIdx.x * 256 + threadIdx.x;
    if (idx < N_NODES) {
        int o = offs[idx] + bsum[idx >> 8];
        offs[idx] = o;
        cur[idx] = o;
    }
    if (idx == 0) offs[N_NODES] = n_edges;
}

// Kernel 3: bucket edge ids by destination
__global__ void fill_elist(const int* __restrict__ dst, int* __restrict__ cur,
                           int* __restrict__ elist, int n) {
    int i = blockIdx.x * blockDim.x + threadIdx.x;
    if (i < n) {
        int d = dst[i];
        int pos = atomicAdd(&cur[d], 1);
        elist[pos] = i;
    }
}

// Kernel 4: per-(node, col-half) relu-sum -> Mv (bf16). One wave handles 128
// cols of one node; 2x the waves of the old version for latency hiding.
__global__ __launch_bounds__(256)
void node_gather_sum(const float* __restrict__ E,
                     const int* __restrict__ offs,
                     const int* __restrict__ elist,
                     unsigned int* __restrict__ Mvb) {
    const int w    = blockIdx.x * 4 + (threadIdx.x >> 6);
    const int node = w >> 1;
    const int half = w & 1;
    const int lane = threadIdx.x & 63;
    if (node >= N_NODES) return;
    const float* Eh = E + half * 128 + lane * 2;
    const int s0 = offs[node];
    const int s1 = offs[node + 1];
    float ax = 0.f, ay = 0.f;
    int j = s0;
    for (; j + 4 <= s1; j += 4) {
        const int e0 = elist[j], e1 = elist[j + 1], e2 = elist[j + 2], e3 = elist[j + 3];
        float2 v0 = *(const float2*)(Eh + (size_t)e0 * HIDDEN);
        float2 v1 = *(const float2*)(Eh + (size_t)e1 * HIDDEN);
        float2 v2 = *(const float2*)(Eh + (size_t)e2 * HIDDEN);
        float2 v3 = *(const float2*)(Eh + (size_t)e3 * HIDDEN);
        ax += fmaxf(v0.x, 0.f) + fmaxf(v1.x, 0.f) + fmaxf(v2.x, 0.f) + fmaxf(v3.x, 0.f);
        ay += fmaxf(v0.y, 0.f) + fmaxf(v1.y, 0.f) + fmaxf(v2.y, 0.f) + fmaxf(v3.y, 0.f);
    }
    for (; j < s1; ++j) {
        float2 v = *(const float2*)(Eh + (size_t)elist[j] * HIDDEN);
        ax += fmaxf(v.x, 0.f);
        ay += fmaxf(v.y, 0.f);
    }
    Mvb[(size_t)node * 128 + half * 64 + lane] = f2bf(ax) | (f2bf(ay) << 16);
}

// Kernel 5: out = (Mv[src] - relu(E[rev])) @ W.T + b   (fused, LDS-staged)
// MFMA operands SWAPPED: D = mfma(Wfrag, Afrag) so each lane holds one edge
// row x 4 consecutive out cols -> float4 epilogue stores.
__global__ __launch_bounds__(256, 3)
void gemm_fused(const float* __restrict__ E,
                const int* __restrict__ src,
                const int* __restrict__ rev,
                const unsigned int* __restrict__ Mvb,
                const ushort_t* __restrict__ Wf,
                const float* __restrict__ bias,
                float* __restrict__ out, int n_edges) {
    __shared__ __align__(16) unsigned char lds[BM * LDSROW];
    const int tid = threadIdx.x;
    const int row0 = blockIdx.x * BM;

    // ---- stage A tile: A[r][k] = Mv[src[r]][k] - relu(E[rev[r]][k]), bf16,
    // XOR-swizzled 16B slots: slot ^= (row & 7)
    {
        const int r  = tid >> 2;
        const int q  = tid & 3;
        const int r7 = r & 7;
        const int gr = row0 + r;
        unsigned char* lrow = lds + r * LDSROW;
        if (gr < n_edges) {
            const int s  = src[gr];
            const int rv = rev[gr];
            const float4* ep = (const float4*)(E + (size_t)rv * HIDDEN + q * 64);
            const uint4* mvp = (const uint4*)(Mvb + (size_t)s * (HIDDEN / 2) + q * 32);
#pragma unroll
            for (int h = 0; h < 2; ++h) {
                float4 ev[8];
                uint4  mv[4];
#pragma unroll
                for (int i = 0; i < 8; ++i) ev[i] = ep[h * 8 + i];
#pragma unroll
                for (int i = 0; i < 4; ++i) mv[i] = mvp[h * 4 + i];
#pragma unroll
                for (int c = 0; c < 4; ++c) {
                    float4 e0 = ev[2 * c], e1 = ev[2 * c + 1];
                    uint4  m  = mv[c];
                    uint4 o;
                    o.x = f2bf(bf2f(m.x & 0xffffu) - fmaxf(e0.x, 0.f)) |
                          (f2bf(bf2f(m.x >> 16)    - fmaxf(e0.y, 0.f)) << 16);
                    o.y = f2bf(bf2f(m.y & 0xffffu) - fmaxf(e0.z, 0.f)) |
                          (f2bf(bf2f(m.y >> 16)    - fmaxf(e0.w, 0.f)) << 16);
                    o.z = f2bf(bf2f(m.z & 0xffffu) - fmaxf(e1.x, 0.f)) |
                          (f2bf(bf2f(m.z >> 16)    - fmaxf(e1.y, 0.f)) << 16);
                    o.w = f2bf(bf2f(m.w & 0xffffu) - fmaxf(e1.z, 0.f)) |
                          (f2bf(bf2f(m.w >> 16)    - fmaxf(e1.w, 0.f)) << 16);
                    const int slot = (q * 8 + h * 4 + c) ^ r7;
                    *(uint4*)(lrow + slot * 16) = o;
                }
            }
        } else {
            uint4 z = {0, 0, 0, 0};
#pragma unroll
            for (int c = 0; c < 8; ++c) *(uint4*)(lrow + ((q * 8 + c) ^ r7) * 16) = z;
        }
    }
    __syncthreads();

    // ---- MFMA: each wave owns 64 rows x 64 cols
    const int lane  = tid & 63;
    const int wid   = tid >> 6;
    const int l15   = lane & 15;
    const int hi16  = lane >> 4;
    const int wcol0 = wid * 64;
    const int r7l   = l15 & 7;

    f32x4 acc[4][4];
#pragma unroll
    for (int m = 0; m < 4; ++m)
#pragma unroll
        for (int n = 0; n < 4; ++n)
            acc[m][n] = (f32x4){0.f, 0.f, 0.f, 0.f};

#pragma unroll 2
    for (int kk = 0; kk < 8; ++kk) {
        const int slotbyte = ((kk * 4 + hi16) ^ r7l) * 16;
        short8 a[4], bfr[4];
#pragma unroll
        for (int m = 0; m < 4; ++m)
            a[m] = *(const short8*)(lds + (m * 16 + l15) * LDSROW + slotbyte);
#pragma unroll
        for (int n = 0; n < 4; ++n)
            bfr[n] = *(const short8*)(Wf + (size_t)((((wid * 4 + n) * 8 + kk) * 64 + lane) << 3));
#pragma unroll
        for (int m = 0; m < 4; ++m)
#pragma unroll
            for (int n = 0; n < 4; ++n)
                acc[m][n] = __builtin_amdgcn_mfma_f32_16x16x32_bf16(bfr[n], a[m], acc[m][n], 0, 0, 0);
    }

    // ---- epilogue: lane holds edge row (l15) x 4 consecutive out cols
    // (hi16*4 + reg). float4 stores.
#pragma unroll
    for (int m = 0; m < 4; ++m) {
        const int row = row0 + m * 16 + l15;
        if (row < n_edges) {
            float* orow = out + (size_t)row * HIDDEN;
#pragma unroll
            for (int n = 0; n < 4; ++n) {
                const int cb = wcol0 + n * 16 + hi16 * 4;
                float4 bv = *(const float4*)(bias + cb);
                float4 o;
                o.x = acc[m][n][0] + bv.x;
                o.y = acc[m][n][1] + bv.y;
                o.z = acc[m][n][2] + bv.z;
                o.w = acc[m][n][3] + bv.w;
                *(float4*)(orow + cb) = o;
            }
        }
    }
}

extern "C" void kernel_launch(void* const* d_in, const int* in_sizes, int n_in,
                              void* d_out, int out_size, void* d_ws, size_t ws_size,
                              hipStream_t stream) {
    const float* E    = (const float*)d_in[0];
    const int*   ei   = (const int*)d_in[1];
    const int*   rev  = (const int*)d_in[2];
    const float* W    = (const float*)d_in[3];
    const float* bias = (const float*)d_in[4];
    float* out = (float*)d_out;
    const int n_edges = in_sizes[2];
    const int* srcI = ei;              // edge_index[0]
    const int* dstI = ei + n_edges;    // edge_index[1]

    char* ws = (char*)d_ws;
    unsigned int* Mvb  = (unsigned int*)(ws + OFF_MVB);
    ushort_t*     Wf   = (ushort_t*)(ws + OFF_WF);
    int*          cnt  = (int*)(ws + OFF_CNT);
    int*          offs = (int*)(ws + OFF_OFFS);
    int*          cur  = (int*)(ws + OFF_CUR);
    int*          elst = (int*)(ws + OFF_ELIST);
    int*          bsum = (int*)(ws + OFF_BSUM);

    hipMemsetAsync(cnt, 0, N_NODES * sizeof(int), stream);

    convert_w_frag<<<(HIDDEN * HIDDEN + 255) / 256, 256, 0, stream>>>(W, Wf, HIDDEN * HIDDEN);

    count_dst<<<(n_edges + 255) / 256, 256, 0, stream>>>(dstI, cnt, n_edges);
    block_scan<<<SCAN_NBLK, 256, 0, stream>>>(cnt, offs, bsum);
    scan_bsum<<<1, 256, 0, stream>>>(bsum, SCAN_NBLK);
    add_base<<<SCAN_NBLK, 256, 0, stream>>>(offs, bsum, cur, n_edges);
    fill_elist<<<(n_edges + 255) / 256, 256, 0, stream>>>(dstI, cur, elst, n_edges);

    const int nwaves = N_NODES * 2;
    node_gather_sum<<<(nwaves + 3) / 4, 256, 0, stream>>>(E, offs, elst, Mvb);

    const int nblk = (n_edges + BM - 1) / BM;
    gemm_fused<<<nblk, 256, 0, stream>>>(E, srcI, rev, Mvb, Wf, bias, out, n_edges);
}

// Round 8
// 286.080 us; speedup vs baseline: 1.6335x; 1.1077x over previous
//
#include <hip/hip_runtime.h>
#include <hip/hip_bf16.h>

typedef unsigned short ushort_t;
typedef __attribute__((ext_vector_type(8))) short short8;
typedef __attribute__((ext_vector_type(4))) float f32x4;

#define HIDDEN 256
#define N_NODES 50000
#define BM 64
#define LDSROW 512   // bf16 row = 512B; XOR-swizzled 16B slots

__device__ __forceinline__ unsigned int f2bf(float f) {
    union { float f; unsigned int i; } v; v.f = f;
    return (v.i + 0x7fffu + ((v.i >> 16) & 1u)) >> 16;
}
__device__ __forceinline__ float bf2f(unsigned int u) {
    union { unsigned int i; float f; } v; v.i = u << 16; return v.f;
}

// ws layout (bytes)
#define OFF_MVB    0u                         // 50000*128 u32 (bf16x2) = 25,600,000
#define OFF_WF     25600000u                  // 65536 bf16 fragment-major
#define OFF_CNT    25731072u                  // int[50000]
#define OFF_OFFS   25931072u                  // int[50001]
#define OFF_CUR    26131076u                  // int[50000]
#define OFF_ELIST  26331076u                  // int[300000]
#define OFF_BSUM   27531076u                  // int[256]

#define SCAN_NBLK ((N_NODES + 255) / 256)     // 196

// Kernel 0: pack W fp32 -> bf16 fragment-major.
// Wf[(((g*8)+kk)*64 + lane)*8 + t] = W[g*16 + (lane&15)][kk*32 + (lane>>4)*8 + t]
__global__ void convert_w_frag(const float* __restrict__ W, ushort_t* __restrict__ Wf, int n) {
    int i = blockIdx.x * blockDim.x + threadIdx.x;
    if (i >= n) return;
    const int t    = i & 7;
    const int lane = (i >> 3) & 63;
    const int kk   = (i >> 9) & 7;
    const int g    = i >> 12;
    const int j = g * 16 + (lane & 15);
    const int k = kk * 32 + ((lane >> 4) & 3) * 8 + t;
    Wf[i] = (ushort_t)f2bf(W[j * HIDDEN + k]);
}

// Kernel 1: histogram of dst
__global__ void count_dst(const int* __restrict__ dst, int* __restrict__ cnt, int n) {
    int i = blockIdx.x * blockDim.x + threadIdx.x;
    if (i < n) atomicAdd(&cnt[dst[i]], 1);
}

// Kernel 2a: per-256-block exclusive scan, block sums out
__global__ __launch_bounds__(256)
void block_scan(const int* __restrict__ cnt, int* __restrict__ offs,
                int* __restrict__ bsum) {
    __shared__ int sh[256];
    const int t = threadIdx.x;
    const int idx = blockIdx.x * 256 + t;
    int v = (idx < N_NODES) ? cnt[idx] : 0;
    sh[t] = v;
    __syncthreads();
    for (int off = 1; off < 256; off <<= 1) {
        int x = (t >= off) ? sh[t - off] : 0;
        __syncthreads();
        sh[t] += x;
        __syncthreads();
    }
    if (idx < N_NODES) offs[idx] = sh[t] - v;
    if (t == 255) bsum[blockIdx.x] = sh[255];
}

// Kernel 2b: exclusive scan of block sums (single block)
__global__ __launch_bounds__(256)
void scan_bsum(int* __restrict__ bsum, int nb) {
    __shared__ int sh[256];
    const int t = threadIdx.x;
    int v = (t < nb) ? bsum[t] : 0;
    sh[t] = v;
    __syncthreads();
    for (int off = 1; off < 256; off <<= 1) {
        int x = (t >= off) ? sh[t - off] : 0;
        __syncthreads();
        sh[t] += x;
        __syncthreads();
    }
    if (t < nb) bsum[t] = sh[t] - v;
}

// Kernel 2c: offs += base; cur = offs; offs[N] = n_edges
__global__ __launch_bounds__(256)
void add_base(int* __restrict__ offs, const int* __restrict__ bsum,
              int* __restrict__ cur, int n_edges) {
    const int idx = blockIdx.x * 256 + threadIdx.x;
    if (idx < N_NODES) {
        int o = offs[idx] + bsum[idx >> 8];
        offs[idx] = o;
        cur[idx] = o;
    }
    if (idx == 0) offs[N_NODES] = n_edges;
}

// Kernel 3: bucket edge ids by destination
__global__ void fill_elist(const int* __restrict__ dst, int* __restrict__ cur,
                           int* __restrict__ elist, int n) {
    int i = blockIdx.x * blockDim.x + threadIdx.x;
    if (i < n) {
        int d = dst[i];
        int pos = atomicAdd(&cur[d], 1);
        elist[pos] = i;
    }
}

// Kernel 4: per-(node, col-half) relu-sum -> Mv (bf16)
__global__ __launch_bounds__(256)
void node_gather_sum(const float* __restrict__ E,
                     const int* __restrict__ offs,
                     const int* __restrict__ elist,
                     unsigned int* __restrict__ Mvb) {
    const int w    = blockIdx.x * 4 + (threadIdx.x >> 6);
    const int node = w >> 1;
    const int half = w & 1;
    const int lane = threadIdx.x & 63;
    if (node >= N_NODES) return;
    const float* Eh = E + half * 128 + lane * 2;
    const int s0 = offs[node];
    const int s1 = offs[node + 1];
    float ax = 0.f, ay = 0.f;
    int j = s0;
    for (; j + 4 <= s1; j += 4) {
        const int e0 = elist[j], e1 = elist[j + 1], e2 = elist[j + 2], e3 = elist[j + 3];
        float2 v0 = *(const float2*)(Eh + (size_t)e0 * HIDDEN);
        float2 v1 = *(const float2*)(Eh + (size_t)e1 * HIDDEN);
        float2 v2 = *(const float2*)(Eh + (size_t)e2 * HIDDEN);
        float2 v3 = *(const float2*)(Eh + (size_t)e3 * HIDDEN);
        ax += fmaxf(v0.x, 0.f) + fmaxf(v1.x, 0.f) + fmaxf(v2.x, 0.f) + fmaxf(v3.x, 0.f);
        ay += fmaxf(v0.y, 0.f) + fmaxf(v1.y, 0.f) + fmaxf(v2.y, 0.f) + fmaxf(v3.y, 0.f);
    }
    for (; j < s1; ++j) {
        float2 v = *(const float2*)(Eh + (size_t)elist[j] * HIDDEN);
        ax += fmaxf(v.x, 0.f);
        ay += fmaxf(v.y, 0.f);
    }
    Mvb[(size_t)node * 128 + half * 64 + lane] = f2bf(ax) | (f2bf(ay) << 16);
}

// Kernel 5: out = (Mv[src] - relu(E[rev])) @ W.T + b   (fused, LDS-staged)
// Staging is wave-per-row: lane l loads E-row at l*16B (1KB coalesced) and
// Mv-row at l*8B (512B coalesced); row indices are wave-uniform (scalar
// loads). MFMA operands swapped so each lane holds one edge row x 4
// consecutive out cols -> float4 epilogue stores.
__global__ __launch_bounds__(256, 3)
void gemm_fused(const float* __restrict__ E,
                const int* __restrict__ src,
                const int* __restrict__ rev,
                const unsigned int* __restrict__ Mvb,
                const ushort_t* __restrict__ Wf,
                const float* __restrict__ bias,
                float* __restrict__ out, int n_edges) {
    __shared__ __align__(16) unsigned char lds[BM * LDSROW];
    const int tid = threadIdx.x;
    const int row0 = blockIdx.x * BM;
    const int lane = tid & 63;
    const int wid  = tid >> 6;

    // ---- stage A tile: A[r][k] = Mv[src[r]][k] - relu(E[rev[r]][k]), bf16,
    // XOR-swizzled 16B slots: slot ^= (row & 7). 16 rows per wave.
    {
        const int wrow = wid * 16;
#pragma unroll
        for (int rr = 0; rr < 16; rr += 4) {
            float4 ev[4];
            uint2  mv[4];
            const int rbase = wrow + rr;
#pragma unroll
            for (int i = 0; i < 4; ++i) {
                int gr = row0 + rbase + i;
                int grc = (gr < n_edges) ? gr : (n_edges - 1);
                const int s  = src[grc];
                const int rv = rev[grc];
                ev[i] = *(const float4*)(E + (size_t)rv * HIDDEN + lane * 4);
                mv[i] = *(const uint2*)(Mvb + (size_t)s * (HIDDEN / 2) + lane * 2);
            }
#pragma unroll
            for (int i = 0; i < 4; ++i) {
                const int r = rbase + i;
                uint2 o;
                o.x = f2bf(bf2f(mv[i].x & 0xffffu) - fmaxf(ev[i].x, 0.f)) |
                      (f2bf(bf2f(mv[i].x >> 16)    - fmaxf(ev[i].y, 0.f)) << 16);
                o.y = f2bf(bf2f(mv[i].y & 0xffffu) - fmaxf(ev[i].z, 0.f)) |
                      (f2bf(bf2f(mv[i].y >> 16)    - fmaxf(ev[i].w, 0.f)) << 16);
                const int slot = (lane >> 1) ^ (r & 7);
                *(uint2*)(lds + r * LDSROW + slot * 16 + (lane & 1) * 8) = o;
            }
        }
    }
    __syncthreads();

    // ---- MFMA: each wave owns 64 rows x 64 cols
    const int l15   = lane & 15;
    const int hi16  = lane >> 4;
    const int wcol0 = wid * 64;
    const int r7l   = l15 & 7;

    f32x4 acc[4][4];
#pragma unroll
    for (int m = 0; m < 4; ++m)
#pragma unroll
        for (int n = 0; n < 4; ++n)
            acc[m][n] = (f32x4){0.f, 0.f, 0.f, 0.f};

#pragma unroll 2
    for (int kk = 0; kk < 8; ++kk) {
        const int slotbyte = ((kk * 4 + hi16) ^ r7l) * 16;
        short8 a[4], bfr[4];
#pragma unroll
        for (int m = 0; m < 4; ++m)
            a[m] = *(const short8*)(lds + (m * 16 + l15) * LDSROW + slotbyte);
#pragma unroll
        for (int n = 0; n < 4; ++n)
            bfr[n] = *(const short8*)(Wf + (size_t)((((wid * 4 + n) * 8 + kk) * 64 + lane) << 3));
#pragma unroll
        for (int m = 0; m < 4; ++m)
#pragma unroll
            for (int n = 0; n < 4; ++n)
                acc[m][n] = __builtin_amdgcn_mfma_f32_16x16x32_bf16(bfr[n], a[m], acc[m][n], 0, 0, 0);
    }

    // ---- epilogue: lane holds edge row (l15) x 4 consecutive out cols
#pragma unroll
    for (int m = 0; m < 4; ++m) {
        const int row = row0 + m * 16 + l15;
        if (row < n_edges) {
            float* orow = out + (size_t)row * HIDDEN;
#pragma unroll
            for (int n = 0; n < 4; ++n) {
                const int cb = wcol0 + n * 16 + hi16 * 4;
                float4 bv = *(const float4*)(bias + cb);
                float4 o;
                o.x = acc[m][n][0] + bv.x;
                o.y = acc[m][n][1] + bv.y;
                o.z = acc[m][n][2] + bv.z;
                o.w = acc[m][n][3] + bv.w;
                *(float4*)(orow + cb) = o;
            }
        }
    }
}

extern "C" void kernel_launch(void* const* d_in, const int* in_sizes, int n_in,
                              void* d_out, int out_size, void* d_ws, size_t ws_size,
                              hipStream_t stream) {
    const float* E    = (const float*)d_in[0];
    const int*   ei   = (const int*)d_in[1];
    const int*   rev  = (const int*)d_in[2];
    const float* W    = (const float*)d_in[3];
    const float* bias = (const float*)d_in[4];
    float* out = (float*)d_out;
    const int n_edges = in_sizes[2];
    const int* srcI = ei;              // edge_index[0]
    const int* dstI = ei + n_edges;    // edge_index[1]

    char* ws = (char*)d_ws;
    unsigned int* Mvb  = (unsigned int*)(ws + OFF_MVB);
    ushort_t*     Wf   = (ushort_t*)(ws + OFF_WF);
    int*          cnt  = (int*)(ws + OFF_CNT);
    int*          offs = (int*)(ws + OFF_OFFS);
    int*          cur  = (int*)(ws + OFF_CUR);
    int*          elst = (int*)(ws + OFF_ELIST);
    int*          bsum = (int*)(ws + OFF_BSUM);

    hipMemsetAsync(cnt, 0, N_NODES * sizeof(int), stream);

    convert_w_frag<<<(HIDDEN * HIDDEN + 255) / 256, 256, 0, stream>>>(W, Wf, HIDDEN * HIDDEN);

    count_dst<<<(n_edges + 255) / 256, 256, 0, stream>>>(dstI, cnt, n_edges);
    block_scan<<<SCAN_NBLK, 256, 0, stream>>>(cnt, offs, bsum);
    scan_bsum<<<1, 256, 0, stream>>>(bsum, SCAN_NBLK);
    add_base<<<SCAN_NBLK, 256, 0, stream>>>(offs, bsum, cur, n_edges);
    fill_elist<<<(n_edges + 255) / 256, 256, 0, stream>>>(dstI, cur, elst, n_edges);

    const int nwaves = N_NODES * 2;
    node_gather_sum<<<(nwaves + 3) / 4, 256, 0, stream>>>(E, offs, elst, Mvb);

    const int nblk = (n_edges + BM - 1) / BM;
    gemm_fused<<<nblk, 256, 0, stream>>>(E, srcI, rev, Mvb, Wf, bias, out, n_edges);
}